// Round 2
// baseline (279.331 us; speedup 1.0000x reference)
//
#include <hip/hip_runtime.h>
#include <hip/hip_bf16.h>

#define B_ 32
#define S_ 2048
#define D_ 512
#define M_ (B_*S_)   // 65536 rows

typedef __bf16 bf16x8 __attribute__((ext_vector_type(8)));
typedef float  f32x4  __attribute__((ext_vector_type(4)));

__device__ __forceinline__ float tanh_fast(float x){
  float e2 = __expf(2.f * x);                    // inf for large x -> rcp=0 -> 1
  return 1.f - 2.f * __builtin_amdgcn_rcpf(e2 + 1.f);
}

__device__ __forceinline__ uint4 cvt8(f32x4 p0, f32x4 p1){
  bf16x8 tt;
  tt[0]=(__bf16)p0[0]; tt[1]=(__bf16)p0[1]; tt[2]=(__bf16)p0[2]; tt[3]=(__bf16)p0[3];
  tt[4]=(__bf16)p1[0]; tt[5]=(__bf16)p1[1]; tt[6]=(__bf16)p1[2]; tt[7]=(__bf16)p1[3];
  return __builtin_bit_cast(uint4, tt);
}

// ---- reorder w_v (fp32 KxN row-major [e*512+d]) into bf16 MFMA B-frag order ----
// frag id f = ks*32 + nt. lane holds B[k = ks*32 + quad*8 + j][n = nt*16 + lm], j=0..7.
__global__ void k_reorder_wv(const float* __restrict__ wv,
                             unsigned short* __restrict__ wvr){
  int frag = blockIdx.x;          // 0..511
  int lane = threadIdx.x;         // 0..63
  int ks = frag >> 5, nt = frag & 31;
  int k0 = ks*32 + (lane>>4)*8;
  int d  = nt*16 + (lane&15);
  bf16x8 t;
  #pragma unroll
  for (int j=0;j<8;++j) t[j] = (__bf16)wv[(k0+j)*D_ + d];
  *reinterpret_cast<uint4*>(wvr + ((size_t)frag*64 + lane)*8) =
      __builtin_bit_cast(uint4, t);
}

// ---- qproj[b,d] = query[b,:] @ w_q[:,d] + bias[d]  (fp32, 4-way K-split) ----
__global__ void k_qproj(const float* __restrict__ q,
                        const float* __restrict__ wq,
                        const float* __restrict__ bias,
                        float* __restrict__ qp){
  int b  = blockIdx.y;
  int t  = threadIdx.x;          // 512
  int dl = t & 127, eg = t >> 7;
  int d  = blockIdx.x*128 + dl;
  __shared__ float qs[D_];
  __shared__ float red[4][128];
  for (int e=t; e<D_; e+=512) qs[e] = q[b*D_+e];
  __syncthreads();
  float acc = 0.f;
  #pragma unroll 8
  for (int i=0;i<128;++i){
    int e = eg*128 + i;
    acc = fmaf(qs[e], wq[(size_t)e*D_+d], acc);
  }
  red[eg][dl] = acc;
  __syncthreads();
  if (eg == 0)
    qp[b*D_+d] = red[0][dl]+red[1][dl]+red[2][dl]+red[3][dl] + bias[d];
}

// ---- fused (value@w_v + qproj + loc) -> tanh -> dot(score_w) -> scores ----
// v3 occupancy restructure: block = 256 thr (4 waves) covers 64 rows x 256
// cols (d-half dh). Two blocks per row-group; partial scores summed in
// k_softmax. Per-wave tile 64x64 -> acc[4][4] = 64 AGPRs (was 128), total
// regs/wave ~145 -> 3 blocks/CU (12 waves/CU) instead of 2 blocks (8 waves).
// BK=64 barrier period, register-dbuf B frags, value staged a period ahead.
__launch_bounds__(256, 3)
__global__ void k_energy(const float* __restrict__ value,
                         const unsigned short* __restrict__ wvr,
                         const float* __restrict__ qp,
                         const float* __restrict__ energy,
                         const float* __restrict__ conv_w,
                         const float* __restrict__ conv_b,
                         const float* __restrict__ score_w,
                         float* __restrict__ sp){
  const int t    = threadIdx.x;
  const int wave = t >> 6;
  const int lane = t & 63;
  const int quad = lane >> 4;
  const int lm   = lane & 15;
  const int rg   = blockIdx.x >> 1;     // row-group (64 rows)
  const int dh   = blockIdx.x & 1;      // d-half (0: cols 0-255, 1: 256-511)
  const int row0 = rg * 64;
  const int b    = row0 >> 11;          // S=2048
  const int s0   = row0 & (S_-1);

  // As[buf][half][mt][o*16+r][8]: frag-ordered A, 64 rows x 64 k bf16 per buf
  __shared__ __align__(16) unsigned short As[2][2][4][64][8];   // 16 KB

  // staging mapping: thread t -> row sr = t>>2, k-octet so = t&3 (within 32-half)
  const int sr  = t >> 2;
  const int so  = t & 3;
  const float* gA = value + (size_t)(row0+sr)*D_ + so*8;
  unsigned short* wA = &As[0][0][sr>>4][so*16 + (sr&15)][0];
  // strides in shorts: half = 2048, buf = 4096

  f32x4 acc[4][4];
  #pragma unroll
  for (int mt=0;mt<4;++mt)
    #pragma unroll
    for (int nt=0;nt<4;++nt)
      acc[mt][nt] = (f32x4){0.f,0.f,0.f,0.f};

  // wave's N-tile base within the 32 d-tiles
  const int ntb = dh*16 + wave*4;
  const unsigned short* bP = wvr + ((size_t)ntb*64 + lane)*8;
  // frag (chunk c, j) at bP + (c*32 + j)*512 shorts

  // prologue: B frags for chunk 0, stage period 0 into buf 0
  bf16x8 bcur[4], bnxt[4];
  #pragma unroll
  for (int n=0;n<4;++n)
    bcur[n] = __builtin_bit_cast(bf16x8,
        *reinterpret_cast<const uint4*>(bP + (size_t)n*512));
  {
    f32x4 p0 = *reinterpret_cast<const f32x4*>(gA);
    f32x4 p1 = *reinterpret_cast<const f32x4*>(gA + 4);
    f32x4 p2 = *reinterpret_cast<const f32x4*>(gA + 32);
    f32x4 p3 = *reinterpret_cast<const f32x4*>(gA + 36);
    *reinterpret_cast<uint4*>(wA)        = cvt8(p0, p1);
    *reinterpret_cast<uint4*>(wA + 2048) = cvt8(p2, p3);
  }
  __syncthreads();

  for (int p=0; p<8; ++p){
    const int buf = p & 1;
    unsigned short* wAp = wA + (buf^1)*4096;

    // value prefetch for period p+1 (consumed at end of this period)
    f32x4 n0, n1, n2, n3;
    if (p < 7){
      const float* g = gA + (p+1)*64;
      n0 = *reinterpret_cast<const f32x4*>(g);
      n1 = *reinterpret_cast<const f32x4*>(g + 4);
      n2 = *reinterpret_cast<const f32x4*>(g + 32);
      n3 = *reinterpret_cast<const f32x4*>(g + 36);
    }

    // prefetch B frags for chunk 2p+1 (consumed after cluster 1)
    #pragma unroll
    for (int n=0;n<4;++n)
      bnxt[n] = __builtin_bit_cast(bf16x8,
          *reinterpret_cast<const uint4*>(bP + (size_t)((2*p+1)*32+n)*512));

    // chunk 2p: A from LDS, MFMA with bcur
    {
      bf16x8 a[4];
      #pragma unroll
      for (int mt=0;mt<4;++mt)
        a[mt] = *reinterpret_cast<const bf16x8*>(&As[buf][0][mt][lane][0]);
      __builtin_amdgcn_s_setprio(1);
      #pragma unroll
      for (int ntl=0;ntl<4;++ntl)
        #pragma unroll
        for (int mt=0;mt<4;++mt)
          acc[mt][ntl] = __builtin_amdgcn_mfma_f32_16x16x32_bf16(a[mt], bcur[ntl], acc[mt][ntl], 0,0,0);
      __builtin_amdgcn_s_setprio(0);
    }

    // prefetch B frags for chunk 2p+2 (first chunk of next period)
    if (p < 7){
      #pragma unroll
      for (int n=0;n<4;++n)
        bcur[n] = __builtin_bit_cast(bf16x8,
            *reinterpret_cast<const uint4*>(bP + (size_t)((2*p+2)*32+n)*512));
    }

    // chunk 2p+1: A from LDS, MFMA with bnxt
    {
      bf16x8 a[4];
      #pragma unroll
      for (int mt=0;mt<4;++mt)
        a[mt] = *reinterpret_cast<const bf16x8*>(&As[buf][1][mt][lane][0]);
      __builtin_amdgcn_s_setprio(1);
      #pragma unroll
      for (int ntl=0;ntl<4;++ntl)
        #pragma unroll
        for (int mt=0;mt<4;++mt)
          acc[mt][ntl] = __builtin_amdgcn_mfma_f32_16x16x32_bf16(a[mt], bnxt[ntl], acc[mt][ntl], 0,0,0);
      __builtin_amdgcn_s_setprio(0);
    }

    // write staged values for period p+1 into the other buffer
    if (p < 7){
      *reinterpret_cast<uint4*>(wAp)        = cvt8(n0, n1);
      *reinterpret_cast<uint4*>(wAp + 2048) = cvt8(n2, n3);
    }
    __syncthreads();
  }

  // epilogue: per-lane d set = dh*256 + wave*64 + ntl*16 + lm
  float sw[4], c0[4], c1[4], c2[4], cb[4], qv[4];
  #pragma unroll
  for (int ntl=0; ntl<4; ++ntl){
    int d = dh*256 + wave*64 + ntl*16 + lm;
    sw[ntl] = score_w[d];
    c0[ntl] = conv_w[d*3+0];
    c1[ntl] = conv_w[d*3+1];
    c2[ntl] = conv_w[d*3+2];
    cb[ntl] = conv_b[d];
    qv[ntl] = qp[b*D_+d];
  }
  float* red = (float*)&As[0][0][0][0][0];   // reuse LDS: 4 waves x 64 rows
  const float* eB = energy + b*S_;
  // loc(d) contribution: only in dh==0 partial? No: conv/q/bias terms are
  // inside tanh per-d, so every d contributes through its own tanh -> both
  // halves need their own d-terms; partials add across d sets. Correct.
  #pragma unroll
  for (int mt=0; mt<4; ++mt){
    #pragma unroll
    for (int r=0;r<4;++r){
      int sl = mt*16 + quad*4 + r;              // C/D layout: row=quad*4+reg
      int s  = s0 + sl;
      float em1 = (s > 0)    ? eB[s-1] : 0.f;
      float e0  =              eB[s];
      float ep1 = (s < S_-1) ? eB[s+1] : 0.f;
      float p = 0.f;
      #pragma unroll
      for (int ntl=0; ntl<4; ++ntl){
        float h = acc[mt][ntl][r] + qv[ntl]
                + fmaf(c0[ntl],em1, fmaf(c1[ntl],e0, fmaf(c2[ntl],ep1, cb[ntl])));
        p = fmaf(sw[ntl], tanh_fast(h), p);
      }
      #pragma unroll
      for (int m=1; m<16; m<<=1) p += __shfl_xor(p, m, 64);   // reduce 16 cols
      if (lm == 0) red[wave*64 + sl] = p;
    }
  }
  __syncthreads();
  if (t < 64)
    sp[(size_t)dh*M_ + row0 + t] = red[t] + red[64+t] + red[128+t] + red[192+t];
}

// ---- softmax over S per batch; sums the two d-half partials ----
__global__ void k_softmax(const float* __restrict__ sp,
                          const float* __restrict__ score_b,
                          float* __restrict__ out_align){
  int b = blockIdx.x, t = threadIdx.x;
  int lane = t & 63, wid = t >> 6;
  float sb = score_b[0];
  float v[8], mx = -3.4e38f;
  #pragma unroll
  for (int i=0;i<8;++i){
    int idx = b*S_ + t + i*256;
    float sc = sp[idx] + sp[M_ + idx] + sb;
    v[i] = sc;
    mx = fmaxf(mx, sc);
  }
  __shared__ float red[4], red2[4];
  #pragma unroll
  for (int m=1;m<64;m<<=1) mx = fmaxf(mx, __shfl_xor(mx, m, 64));
  if (lane==0) red[wid] = mx;
  __syncthreads();
  mx = fmaxf(fmaxf(red[0],red[1]), fmaxf(red[2],red[3]));
  float sum = 0.f;
  #pragma unroll
  for (int i=0;i<8;++i){ v[i] = __expf(v[i]-mx); sum += v[i]; }
  #pragma unroll
  for (int m=1;m<64;m<<=1) sum += __shfl_xor(sum, m, 64);
  if (lane==0) red2[wid] = sum;
  __syncthreads();
  sum = red2[0]+red2[1]+red2[2]+red2[3];
  float inv = 1.f/sum;
  #pragma unroll
  for (int i=0;i<8;++i) out_align[b*S_ + t + i*256] = v[i]*inv;
}

// ---- context partials: block (sc,b) covers 64 s rows; align via LDS ----
__global__ void k_ctx_part(const float* __restrict__ value,
                           const float* __restrict__ align,
                           float* __restrict__ cpart){
  int b = blockIdx.y, sc = blockIdx.x;    // sc 0..31
  int t = threadIdx.x;
  int r = t >> 7;            // 0..1 (s subgroup)
  int c = (t & 127) * 4;     // d base, 4 floats = 16B per thread
  __shared__ float al[64];
  if (t < 64) al[t] = align[b*S_ + sc*64 + t];
  __syncthreads();
  f32x4 acc = (f32x4){0.f,0.f,0.f,0.f};
  const float* vbase = value + ((size_t)(b*S_ + sc*64 + r))*D_ + c;
  #pragma unroll 8
  for (int i=0;i<32;++i){
    f32x4 v = *reinterpret_cast<const f32x4*>(vbase + (size_t)(2*i)*D_);
    acc += al[2*i+r] * v;
  }
  __shared__ float lred[2][D_];
  #pragma unroll
  for (int j=0;j<4;++j) lred[r][c+j] = acc[j];
  __syncthreads();
  if (r == 0){
    #pragma unroll
    for (int j=0;j<4;++j)
      cpart[((size_t)(b*32+sc))*D_ + c + j] = lred[0][c+j] + lred[1][c+j];
  }
}

__global__ void k_ctx_reduce(const float* __restrict__ cpart,
                             float* __restrict__ out_ctx){
  int idx = blockIdx.x*256 + threadIdx.x;   // 0..16383
  int b = idx >> 9, d = idx & 511;
  float s = 0.f;
  #pragma unroll
  for (int j=0;j<32;++j) s += cpart[((size_t)(b*32+j))*D_ + d];
  out_ctx[idx] = s;
}

extern "C" void kernel_launch(void* const* d_in, const int* in_sizes, int n_in,
                              void* d_out, int out_size, void* d_ws, size_t ws_size,
                              hipStream_t stream){
  const float* query   = (const float*)d_in[0];
  const float* value   = (const float*)d_in[1];
  const float* energy  = (const float*)d_in[2];
  const float* conv_w  = (const float*)d_in[3];
  const float* conv_b  = (const float*)d_in[4];
  const float* w_q     = (const float*)d_in[5];
  const float* w_v     = (const float*)d_in[6];
  const float* bias    = (const float*)d_in[7];
  const float* score_w = (const float*)d_in[8];
  const float* score_b = (const float*)d_in[9];

  char* ws = (char*)d_ws;
  unsigned short* wvr = (unsigned short*)(ws);            // 512 KB (bf16 frags)
  float* qp    = (float*)(ws + (512<<10));                // 64 KB
  float* sp    = (float*)(ws + (576<<10));                // 512 KB (2 x 65536 f32)
  float* cpart = (float*)(ws + (1088<<10));               // 2 MB (32 x 32 x 512 f32)
  // total ~3.1 MB

  float* out_ctx   = (float*)d_out;                       // [B, D] fp32
  float* out_align = out_ctx + B_*D_;                     // [B, S] fp32

  k_reorder_wv<<<dim3(512),      dim3(64),  0, stream>>>(w_v, wvr);
  k_qproj     <<<dim3(4,32),     dim3(512), 0, stream>>>(query, w_q, bias, qp);
  k_energy    <<<dim3(M_/32),    dim3(256), 0, stream>>>(value, wvr, qp, energy,
                                                         conv_w, conv_b, score_w, sp);
  k_softmax   <<<dim3(B_),       dim3(256), 0, stream>>>(sp, score_b, out_align);
  k_ctx_part  <<<dim3(32,B_),    dim3(256), 0, stream>>>(value, out_align, cpart);
  k_ctx_reduce<<<dim3(B_*D_/256),dim3(256), 0, stream>>>(cpart, out_ctx);
}

// Round 3
// 269.774 us; speedup vs baseline: 1.0354x; 1.0354x over previous
//
#include <hip/hip_runtime.h>
#include <hip/hip_bf16.h>

#define B_ 32
#define S_ 2048
#define D_ 512
#define M_ (B_*S_)   // 65536 rows

typedef __bf16 bf16x8 __attribute__((ext_vector_type(8)));
typedef float  f32x4  __attribute__((ext_vector_type(4)));

__device__ __forceinline__ float tanh_fast(float x){
  float e2 = __expf(2.f * x);                    // inf for large x -> rcp=0 -> 1
  return 1.f - 2.f * __builtin_amdgcn_rcpf(e2 + 1.f);
}

__device__ __forceinline__ bf16x8 pack8(f32x4 r0, f32x4 r1){
  bf16x8 t;
  t[0]=(__bf16)r0[0]; t[1]=(__bf16)r0[1]; t[2]=(__bf16)r0[2]; t[3]=(__bf16)r0[3];
  t[4]=(__bf16)r1[0]; t[5]=(__bf16)r1[1]; t[6]=(__bf16)r1[2]; t[7]=(__bf16)r1[3];
  return t;
}

// async 16B/lane global->LDS DMA (wave-uniform LDS base + lane*16)
__device__ __forceinline__ void gl_lds16(const float* g, float* l){
  __builtin_amdgcn_global_load_lds(
      (const __attribute__((address_space(1))) void*)g,
      (__attribute__((address_space(3))) void*)l, 16, 0, 0);
}

// ---- reorder w_v (fp32 KxN row-major [e*512+d]) into bf16 MFMA B-frag order ----
// frag id f = ks*32 + nt. lane holds B[k = ks*32 + quad*8 + j][n = nt*16 + lm], j=0..7.
__global__ void k_reorder_wv(const float* __restrict__ wv,
                             unsigned short* __restrict__ wvr){
  int frag = blockIdx.x;          // 0..511
  int lane = threadIdx.x;         // 0..63
  int ks = frag >> 5, nt = frag & 31;
  int k0 = ks*32 + (lane>>4)*8;
  int d  = nt*16 + (lane&15);
  bf16x8 t;
  #pragma unroll
  for (int j=0;j<8;++j) t[j] = (__bf16)wv[(k0+j)*D_ + d];
  *reinterpret_cast<uint4*>(wvr + ((size_t)frag*64 + lane)*8) =
      __builtin_bit_cast(uint4, t);
}

// ---- qproj[b,d] = query[b,:] @ w_q[:,d] + bias[d]  (fp32, 4-way K-split) ----
__global__ void k_qproj(const float* __restrict__ q,
                        const float* __restrict__ wq,
                        const float* __restrict__ bias,
                        float* __restrict__ qp){
  int b  = blockIdx.y;
  int t  = threadIdx.x;          // 512
  int dl = t & 127, eg = t >> 7;
  int d  = blockIdx.x*128 + dl;
  __shared__ float qs[D_];
  __shared__ float red[4][128];
  for (int e=t; e<D_; e+=512) qs[e] = q[b*D_+e];
  __syncthreads();
  float acc = 0.f;
  #pragma unroll 8
  for (int i=0;i<128;++i){
    int e = eg*128 + i;
    acc = fmaf(qs[e], wq[(size_t)e*D_+d], acc);
  }
  red[eg][dl] = acc;
  __syncthreads();
  if (eg == 0)
    qp[b*D_+d] = red[0][dl]+red[1][dl]+red[2][dl]+red[3][dl] + bias[d];
}

// ---- fused (value@w_v + qproj + loc) -> tanh -> dot(score_w) -> scores ----
// v4: value staged via global_load_lds (async DMA, f32) -> 16KB/block in
// flight per period (vs 512B/CU with register staging) -> BW-saturating.
// LDS [64 rows][64 k] f32 per buffer, XOR-swizzled 16B slots:
//   physical p = logical q ^ f(row),  f(row) = ((row&7)<<1)|((row>>3)&1)
// DMA writes linear (lane*16B); the per-lane GLOBAL source is pre-swizzled
// (rule #21). Consumer ds_read applies the same XOR -> even bank spread.
// Waves convert their A-frags f32->bf16 (hides under MFMA, separate pipes).
// B frags register-double-buffered from L2 as before.
__launch_bounds__(256, 2)
__global__ void k_energy(const float* __restrict__ value,
                         const unsigned short* __restrict__ wvr,
                         const float* __restrict__ qp,
                         const float* __restrict__ energy,
                         const float* __restrict__ conv_w,
                         const float* __restrict__ conv_b,
                         const float* __restrict__ score_w,
                         float* __restrict__ scores){
  const int t    = threadIdx.x;
  const int wave = t >> 6;
  const int lane = t & 63;
  const int quad = lane >> 4;
  const int lm   = lane & 15;
  const int row0 = blockIdx.x * 64;
  const int b    = row0 >> 11;          // S=2048
  const int s0   = row0 & (S_-1);

  __shared__ __align__(16) float Af[2][4096];   // 2 x 16KB (64 rows x 64 k f32)

  // ---- staging source offsets: wave w stages rows 16w..16w+15 ----
  // instr i (0..3): lane writes LDS 16B-slot s16=(w*4+i)*64+lane ->
  // row=(w*4+i)*4+quad, phys slot=lm -> logical q = lm ^ f(row)
  int soff[4];
  #pragma unroll
  for (int i=0;i<4;++i){
    int rq  = 4*i + quad;                       // row sel within wave
    int f   = ((rq&7)<<1) | (rq>>3);
    soff[i] = (row0 + wave*16 + rq)*D_ + ((lm ^ f)<<2);
  }

  // ---- consumer slot constants (per lane) ----
  const int fl  = ((lm&7)<<1) | (lm>>3);
  const int p00 = (quad*2)     ^ fl;            // h=0, j=0
  const int p01 = (quad*2 + 1) ^ fl;            // h=0, j=1
  // h=1 slots are p00^8, p01^8

  f32x4 acc[4][8];
  #pragma unroll
  for (int mt=0;mt<4;++mt)
    #pragma unroll
    for (int nt=0;nt<8;++nt)
      acc[mt][nt] = (f32x4){0.f,0.f,0.f,0.f};

  const unsigned short* bP = wvr + ((size_t)(wave*8)*64 + lane)*8;
  // B frag (chunk c, ntl) at bP + (c*32+ntl)*512 shorts

  // prologue: DMA period 0 into buf 0; preload B(0)
  #pragma unroll
  for (int i=0;i<4;++i)
    gl_lds16(value + soff[i], &Af[0][(wave*4+i)*256]);
  bf16x8 b0[8], b1[8];
  #pragma unroll
  for (int n=0;n<8;++n)
    b0[n] = __builtin_bit_cast(bf16x8,
        *reinterpret_cast<const uint4*>(bP + (size_t)n*512));
  __syncthreads();

  for (int p=0; p<8; ++p){
    const int buf = p & 1;

    // async DMA next period's 64 k-cols into the other buffer
    if (p < 7){
      #pragma unroll
      for (int i=0;i<4;++i)
        gl_lds16(value + soff[i] + (p+1)*64, &Af[buf^1][(wave*4+i)*256]);
    }

    // B frags for chunk 2p+1 (consumed in cluster 2)
    #pragma unroll
    for (int n=0;n<8;++n)
      b1[n] = __builtin_bit_cast(bf16x8,
          *reinterpret_cast<const uint4*>(bP + (size_t)((2*p+1)*32+n)*512));

    // A frags h=0 (k 0..31 of this 64-k period), f32 -> bf16
    bf16x8 a[4];
    #pragma unroll
    for (int mt=0;mt<4;++mt){
      const float* base = &Af[buf][(mt*16+lm)*64];
      f32x4 r0 = *reinterpret_cast<const f32x4*>(base + (p00<<2));
      f32x4 r1 = *reinterpret_cast<const f32x4*>(base + (p01<<2));
      a[mt] = pack8(r0, r1);
    }
    __builtin_amdgcn_s_setprio(1);
    #pragma unroll
    for (int ntl=0;ntl<8;++ntl)
      #pragma unroll
      for (int mt=0;mt<4;++mt)
        acc[mt][ntl] = __builtin_amdgcn_mfma_f32_16x16x32_bf16(a[mt], b0[ntl], acc[mt][ntl], 0,0,0);
    __builtin_amdgcn_s_setprio(0);

    // B frags for chunk 2p+2 (cluster 1 of next period)
    if (p < 7){
      #pragma unroll
      for (int n=0;n<8;++n)
        b0[n] = __builtin_bit_cast(bf16x8,
            *reinterpret_cast<const uint4*>(bP + (size_t)((2*p+2)*32+n)*512));
    }

    // A frags h=1 (k 32..63)
    #pragma unroll
    for (int mt=0;mt<4;++mt){
      const float* base = &Af[buf][(mt*16+lm)*64];
      f32x4 r0 = *reinterpret_cast<const f32x4*>(base + ((p00^8)<<2));
      f32x4 r1 = *reinterpret_cast<const f32x4*>(base + ((p01^8)<<2));
      a[mt] = pack8(r0, r1);
    }
    __builtin_amdgcn_s_setprio(1);
    #pragma unroll
    for (int ntl=0;ntl<8;++ntl)
      #pragma unroll
      for (int mt=0;mt<4;++mt)
        acc[mt][ntl] = __builtin_amdgcn_mfma_f32_16x16x32_bf16(a[mt], b1[ntl], acc[mt][ntl], 0,0,0);
    __builtin_amdgcn_s_setprio(0);

    __syncthreads();   // drains DMA (vmcnt 0) -> buf^1 valid for all waves
  }

  // epilogue: per-lane d set = wave*128 + ntl*16 + lm
  float sw[8], c0[8], c1[8], c2[8], cb[8], qv[8];
  #pragma unroll
  for (int ntl=0; ntl<8; ++ntl){
    int d = wave*128 + ntl*16 + lm;
    sw[ntl] = score_w[d];
    c0[ntl] = conv_w[d*3+0];
    c1[ntl] = conv_w[d*3+1];
    c2[ntl] = conv_w[d*3+2];
    cb[ntl] = conv_b[d];
    qv[ntl] = qp[b*D_+d];
  }
  float* red = &Af[0][0];    // reuse LDS: 4 waves x 64 rows (last reads hit Af[1])
  const float* eB = energy + b*S_;
  #pragma unroll
  for (int mt=0; mt<4; ++mt){
    #pragma unroll
    for (int r=0;r<4;++r){
      int sl = mt*16 + quad*4 + r;              // C/D layout: row=quad*4+reg
      int s  = s0 + sl;
      float em1 = (s > 0)    ? eB[s-1] : 0.f;
      float e0  =              eB[s];
      float ep1 = (s < S_-1) ? eB[s+1] : 0.f;
      float p = 0.f;
      #pragma unroll
      for (int ntl=0; ntl<8; ++ntl){
        float h = acc[mt][ntl][r] + qv[ntl]
                + fmaf(c0[ntl],em1, fmaf(c1[ntl],e0, fmaf(c2[ntl],ep1, cb[ntl])));
        p = fmaf(sw[ntl], tanh_fast(h), p);
      }
      #pragma unroll
      for (int m=1; m<16; m<<=1) p += __shfl_xor(p, m, 64);   // reduce 16 cols
      if (lm == 0) red[wave*64 + sl] = p;
    }
  }
  __syncthreads();
  if (t < 64)
    scores[row0 + t] = red[t] + red[64+t] + red[128+t] + red[192+t];
}

// ---- softmax over S per batch; align written straight to d_out (fp32) ----
__global__ void k_softmax(const float* __restrict__ sp,
                          const float* __restrict__ score_b,
                          float* __restrict__ out_align){
  int b = blockIdx.x, t = threadIdx.x;
  int lane = t & 63, wid = t >> 6;
  float sb = score_b[0];
  float v[8], mx = -3.4e38f;
  #pragma unroll
  for (int i=0;i<8;++i){
    float sc = sp[b*S_ + t + i*256] + sb;
    v[i] = sc;
    mx = fmaxf(mx, sc);
  }
  __shared__ float red[4], red2[4];
  #pragma unroll
  for (int m=1;m<64;m<<=1) mx = fmaxf(mx, __shfl_xor(mx, m, 64));
  if (lane==0) red[wid] = mx;
  __syncthreads();
  mx = fmaxf(fmaxf(red[0],red[1]), fmaxf(red[2],red[3]));
  float sum = 0.f;
  #pragma unroll
  for (int i=0;i<8;++i){ v[i] = __expf(v[i]-mx); sum += v[i]; }
  #pragma unroll
  for (int m=1;m<64;m<<=1) sum += __shfl_xor(sum, m, 64);
  if (lane==0) red2[wid] = sum;
  __syncthreads();
  sum = red2[0]+red2[1]+red2[2]+red2[3];
  float inv = 1.f/sum;
  #pragma unroll
  for (int i=0;i<8;++i) out_align[b*S_ + t + i*256] = v[i]*inv;
}

// ---- context partials: block (sc,b) covers 64 s rows; align via LDS ----
__global__ void k_ctx_part(const float* __restrict__ value,
                           const float* __restrict__ align,
                           float* __restrict__ cpart){
  int b = blockIdx.y, sc = blockIdx.x;    // sc 0..31
  int t = threadIdx.x;
  int r = t >> 7;            // 0..1 (s subgroup)
  int c = (t & 127) * 4;     // d base, 4 floats = 16B per thread
  __shared__ float al[64];
  if (t < 64) al[t] = align[b*S_ + sc*64 + t];
  __syncthreads();
  f32x4 acc = (f32x4){0.f,0.f,0.f,0.f};
  const float* vbase = value + ((size_t)(b*S_ + sc*64 + r))*D_ + c;
  #pragma unroll 8
  for (int i=0;i<32;++i){
    f32x4 v = *reinterpret_cast<const f32x4*>(vbase + (size_t)(2*i)*D_);
    acc += al[2*i+r] * v;
  }
  __shared__ float lred[2][D_];
  #pragma unroll
  for (int j=0;j<4;++j) lred[r][c+j] = acc[j];
  __syncthreads();
  if (r == 0){
    #pragma unroll
    for (int j=0;j<4;++j)
      cpart[((size_t)(b*32+sc))*D_ + c + j] = lred[0][c+j] + lred[1][c+j];
  }
}

__global__ void k_ctx_reduce(const float* __restrict__ cpart,
                             float* __restrict__ out_ctx){
  int idx = blockIdx.x*256 + threadIdx.x;   // 0..16383
  int b = idx >> 9, d = idx & 511;
  float s = 0.f;
  #pragma unroll
  for (int j=0;j<32;++j) s += cpart[((size_t)(b*32+j))*D_ + d];
  out_ctx[idx] = s;
}

extern "C" void kernel_launch(void* const* d_in, const int* in_sizes, int n_in,
                              void* d_out, int out_size, void* d_ws, size_t ws_size,
                              hipStream_t stream){
  const float* query   = (const float*)d_in[0];
  const float* value   = (const float*)d_in[1];
  const float* energy  = (const float*)d_in[2];
  const float* conv_w  = (const float*)d_in[3];
  const float* conv_b  = (const float*)d_in[4];
  const float* w_q     = (const float*)d_in[5];
  const float* w_v     = (const float*)d_in[6];
  const float* bias    = (const float*)d_in[7];
  const float* score_w = (const float*)d_in[8];
  const float* score_b = (const float*)d_in[9];

  char* ws = (char*)d_ws;
  unsigned short* wvr = (unsigned short*)(ws);            // 512 KB (bf16 frags)
  float* qp    = (float*)(ws + (512<<10));                // 64 KB
  float* sp    = (float*)(ws + (576<<10));                // 256 KB (65536 f32)
  float* cpart = (float*)(ws + (832<<10));                // 2 MB (32 x 32 x 512 f32)
  // total ~2.85 MB

  float* out_ctx   = (float*)d_out;                       // [B, D] fp32
  float* out_align = out_ctx + B_*D_;                     // [B, S] fp32

  k_reorder_wv<<<dim3(512),      dim3(64),  0, stream>>>(w_v, wvr);
  k_qproj     <<<dim3(4,32),     dim3(512), 0, stream>>>(query, w_q, bias, qp);
  k_energy    <<<dim3(M_/64),    dim3(256), 0, stream>>>(value, wvr, qp, energy,
                                                         conv_w, conv_b, score_w, sp);
  k_softmax   <<<dim3(B_),       dim3(256), 0, stream>>>(sp, score_b, out_align);
  k_ctx_part  <<<dim3(32,B_),    dim3(256), 0, stream>>>(value, out_align, cpart);
  k_ctx_reduce<<<dim3(B_*D_/256),dim3(256), 0, stream>>>(cpart, out_ctx);
}